// Round 1
// baseline (700.869 us; speedup 1.0000x reference)
//
#include <hip/hip_runtime.h>
#include <math.h>

#define B_ 2
#define H_ 8
#define L_ 2048
#define D_ 64
#define BM 16
#define BN 64
#define NT (L_ / BN)   // 32 column tiles
#define KPAD 68        // 68*4 = 272B row stride: 16B-aligned, conflict-free b128

struct Lds {
  float attn[BM][L_];      // 128 KB unnormalized attn buffer
  float kt[BN][KPAD];      // 17 KB K tile
  float qt[BM][KPAD];      // 4.25 KB Q block
  float muv[2][D_];        // mu[0/1][h][:]
  float rq0[BM], rq1[BM];  // per-row constants
  float rowsum[BM];
};

// Precompute per-column constants ck0/ck1 = s*|k - mu_c|^2 - neg  into d_ws.
__global__ __launch_bounds__(256) void colconst_kernel(
    const float* __restrict__ k, const float* __restrict__ mask,
    const float* __restrict__ mu, float2* __restrict__ ck)
{
  int bh = blockIdx.x >> 3;                       // 0..15
  int c  = (blockIdx.x & 7) * 256 + threadIdx.x;  // column 0..2047
  int b  = bh >> 3, h = bh & 7;
  const float s = -0.0625f;  // -0.5 / sqrt(64)
  const float* kp  = k  + ((size_t)bh * L_ + c) * D_;
  const float* mu0 = mu + (size_t)h * D_;
  const float* mu1 = mu + (size_t)(H_ * D_) + (size_t)h * D_;
  float s0 = 0.f, s1 = 0.f;
#pragma unroll
  for (int d = 0; d < D_; d += 4) {
    float4 kv = *reinterpret_cast<const float4*>(kp + d);
    float4 m0 = *reinterpret_cast<const float4*>(mu0 + d);
    float4 m1 = *reinterpret_cast<const float4*>(mu1 + d);
    float a;
    a = kv.x - m0.x; s0 += a * a;
    a = kv.y - m0.y; s0 += a * a;
    a = kv.z - m0.z; s0 += a * a;
    a = kv.w - m0.w; s0 += a * a;
    a = kv.x - m1.x; s1 += a * a;
    a = kv.y - m1.y; s1 += a * a;
    a = kv.z - m1.z; s1 += a * a;
    a = kv.w - m1.w; s1 += a * a;
  }
  float neg = 1.0e6f * (1.0f - mask[(size_t)b * L_ + c]);
  ck[(size_t)bh * L_ + c] = make_float2(s * s0 - neg, s * s1 - neg);
}

template <bool USE_WS>
__global__ __launch_bounds__(256) void mg_kernel(
    const float* __restrict__ q, const float* __restrict__ k,
    const float* __restrict__ mask, const float* __restrict__ mu,
    const float* __restrict__ pi, const float2* __restrict__ ckw,
    float* __restrict__ out)
{
  extern __shared__ __align__(16) char smem_raw[];
  Lds& S = *reinterpret_cast<Lds*>(smem_raw);

  const int t = threadIdx.x;
  // XCD-chunked swizzle: 2048 WGs, 8 XCDs -> XCD i gets contiguous vwg chunk
  int bid = blockIdx.x;
  int vwg = (bid & 7) * 256 + (bid >> 3);
  int bh  = vwg >> 7;        // 0..15
  int rb  = vwg & 127;       // row block within (b,h)
  int b = bh >> 3, h = bh & 7;
  int row0 = rb * BM;

  const float s   = -0.0625f;
  const float m2s = 0.125f;  // -2*s

  const float* qb    = q + ((size_t)bh * L_ + row0) * D_;
  const float* kb    = k + (size_t)bh * L_ * D_;
  const float* maskb = mask + (size_t)b * L_;
  const float2* ckb  = USE_WS ? (ckw + (size_t)bh * L_) : nullptr;

  float pi0 = fminf(fmaxf(pi[0], 0.f), 1.f);
  float pi1 = fminf(fmaxf(pi[1], 0.f), 1.f);

  // prefetch K tile 0 into registers
  float4 kreg[4];
  {
    const float4* src = reinterpret_cast<const float4*>(kb);
#pragma unroll
    for (int i = 0; i < 4; ++i) kreg[i] = src[t + 256 * i];
  }

  // stage Q block (16x64) and mu (2x64)
  {
    float4 v = reinterpret_cast<const float4*>(qb)[t];
    int r = t >> 4, d = (t & 15) * 4;
    *reinterpret_cast<float4*>(&S.qt[r][d]) = v;
  }
  if (t < 2 * D_) {
    int comp = t >> 6, d = t & 63;
    S.muv[comp][d] = mu[(size_t)comp * (H_ * D_) + (size_t)h * D_ + d];
  }
  __syncthreads();

  // per-row constants: rq_c = s*q^2 + 2s*(q . mu_c)
  if (t < BM) {
    float a0 = 0.f, a1 = 0.f, a2 = 0.f;
    for (int d = 0; d < D_; ++d) {
      float qv = S.qt[t][d];
      a0 += qv * qv;
      a1 += qv * S.muv[0][d];
      a2 += qv * S.muv[1][d];
    }
    S.rq0[t] = s * a0 + 2.f * s * a1;
    S.rq1[t] = s * a0 + 2.f * s * a2;
  }
  __syncthreads();

  const int c = t & 63;   // column within tile (lane)
  const int w = t >> 6;   // wave id -> rows 4w..4w+3
  float rq0r[4], rq1r[4];
#pragma unroll
  for (int rj = 0; rj < 4; ++rj) {
    rq0r[rj] = S.rq0[4 * w + rj];
    rq1r[rj] = S.rq1[4 * w + rj];
  }

  float acc_sum[4] = {0.f, 0.f, 0.f, 0.f};

  for (int j = 0; j < NT; ++j) {
    __syncthreads();  // previous tile compute done -> safe to overwrite kt
#pragma unroll
    for (int i = 0; i < 4; ++i) {
      int idx = t + 256 * i;
      int m = idx >> 4, d = (idx & 15) * 4;
      *reinterpret_cast<float4*>(&S.kt[m][d]) = kreg[i];
    }
    __syncthreads();  // kt ready
    if (j + 1 < NT) {  // prefetch next tile (latency hidden under compute)
      const float4* src = reinterpret_cast<const float4*>(kb) + (size_t)(j + 1) * 1024;
#pragma unroll
      for (int i = 0; i < 4; ++i) kreg[i] = src[t + 256 * i];
    }

    float ck0, ck1, neg = 0.f;
    if (USE_WS) {
      float2 cc = ckb[j * BN + c];
      ck0 = cc.x; ck1 = cc.y;
    } else {
      neg = 1.0e6f * (1.0f - maskb[j * BN + c]);
    }

    float dot0 = 0.f, dot1 = 0.f, dot2 = 0.f, dot3 = 0.f;
    float s0 = 0.f, s1 = 0.f;
#pragma unroll
    for (int kk = 0; kk < D_; kk += 4) {
      float4 kv = *reinterpret_cast<const float4*>(&S.kt[c][kk]);
      if (!USE_WS) {
        float4 m0 = *reinterpret_cast<const float4*>(&S.muv[0][kk]);
        float4 m1 = *reinterpret_cast<const float4*>(&S.muv[1][kk]);
        float a;
        a = kv.x - m0.x; s0 += a * a;
        a = kv.y - m0.y; s0 += a * a;
        a = kv.z - m0.z; s0 += a * a;
        a = kv.w - m0.w; s0 += a * a;
        a = kv.x - m1.x; s1 += a * a;
        a = kv.y - m1.y; s1 += a * a;
        a = kv.z - m1.z; s1 += a * a;
        a = kv.w - m1.w; s1 += a * a;
      }
      float4 q0 = *reinterpret_cast<const float4*>(&S.qt[4 * w + 0][kk]);
      float4 q1 = *reinterpret_cast<const float4*>(&S.qt[4 * w + 1][kk]);
      float4 q2 = *reinterpret_cast<const float4*>(&S.qt[4 * w + 2][kk]);
      float4 q3 = *reinterpret_cast<const float4*>(&S.qt[4 * w + 3][kk]);
      dot0 += q0.x * kv.x + q0.y * kv.y + q0.z * kv.z + q0.w * kv.w;
      dot1 += q1.x * kv.x + q1.y * kv.y + q1.z * kv.z + q1.w * kv.w;
      dot2 += q2.x * kv.x + q2.y * kv.y + q2.z * kv.z + q2.w * kv.w;
      dot3 += q3.x * kv.x + q3.y * kv.y + q3.z * kv.z + q3.w * kv.w;
    }
    if (!USE_WS) { ck0 = s * s0 - neg; ck1 = s * s1 - neg; }

    float dots[4] = {dot0, dot1, dot2, dot3};
#pragma unroll
    for (int rj = 0; rj < 4; ++rj) {
      float dd = m2s * dots[rj];
      float e0 = __expf(rq0r[rj] + ck0 + dd);
      float e1 = __expf(rq1r[rj] + ck1 + dd);
      float a  = pi0 * e0 + pi1 * e1;
      S.attn[4 * w + rj][j * BN + c] = a;
      acc_sum[rj] += a;
    }
  }

  // row sums: reduce across 64 lanes (cols), per wave's 4 rows
#pragma unroll
  for (int rj = 0; rj < 4; ++rj) {
    float v = acc_sum[rj];
#pragma unroll
    for (int off = 32; off; off >>= 1) v += __shfl_xor(v, off, 64);
    if (c == 0) S.rowsum[4 * w + rj] = v;
  }
  __syncthreads();

  // normalized write-out: float4, lane-contiguous (1 KB per wave-instr)
  float* ob = out + ((size_t)bh * L_ + row0) * L_;
#pragma unroll
  for (int rj = 0; rj < 4; ++rj) {
    int r = 4 * w + rj;
    float inv = 1.0f / S.rowsum[r];
#pragma unroll
    for (int g = 0; g < 8; ++g) {
      int col = g * 256 + 4 * c;
      float4 v = *reinterpret_cast<const float4*>(&S.attn[r][col]);
      v.x *= inv; v.y *= inv; v.z *= inv; v.w *= inv;
      *reinterpret_cast<float4*>(&ob[(size_t)r * L_ + col]) = v;
    }
  }
}

extern "C" void kernel_launch(void* const* d_in, const int* in_sizes, int n_in,
                              void* d_out, int out_size, void* d_ws, size_t ws_size,
                              hipStream_t stream) {
  const float* q    = (const float*)d_in[0];
  const float* k    = (const float*)d_in[1];
  const float* mask = (const float*)d_in[2];
  const float* mu   = (const float*)d_in[3];
  const float* pi   = (const float*)d_in[4];
  float* out = (float*)d_out;

  const size_t smem = sizeof(Lds);
  const size_t ck_bytes = (size_t)B_ * H_ * L_ * sizeof(float2);
  const bool use_ws = (ws_size >= ck_bytes) && (d_ws != nullptr);

  if (use_ws) {
    (void)hipFuncSetAttribute(reinterpret_cast<const void*>(&mg_kernel<true>),
                              hipFuncAttributeMaxDynamicSharedMemorySize, (int)smem);
    colconst_kernel<<<dim3(B_ * H_ * 8), dim3(256), 0, stream>>>(k, mask, mu, (float2*)d_ws);
    mg_kernel<true><<<dim3(B_ * H_ * (L_ / BM)), dim3(256), smem, stream>>>(
        q, k, mask, mu, pi, (const float2*)d_ws, out);
  } else {
    (void)hipFuncSetAttribute(reinterpret_cast<const void*>(&mg_kernel<false>),
                              hipFuncAttributeMaxDynamicSharedMemorySize, (int)smem);
    mg_kernel<false><<<dim3(B_ * H_ * (L_ / BM)), dim3(256), smem, stream>>>(
        q, k, mask, mu, pi, nullptr, out);
  }
}

// Round 2
// 268.536 us; speedup vs baseline: 2.6100x; 2.6100x over previous
//
#include <hip/hip_runtime.h>
#include <math.h>

#define B_ 2
#define H_ 8
#define L_ 2048
#define D_ 64
#define BM 16          // rows per WG
#define BN 256         // cols per K-tile iter
#define NJ (L_ / BN)   // 8 iters

typedef __attribute__((address_space(3))) void lds_void_t;
typedef const __attribute__((address_space(1))) void gbl_void_t;

#define GLL16(gp, lp) __builtin_amdgcn_global_load_lds( \
    (gbl_void_t*)(gp), (lds_void_t*)(lp), 16, 0, 0)

struct LdsT {
  float4 kt[BN * 16];     // 64 KB; idx = col*16 + (kq ^ (col&15))
  float4 qt[BM * 16];     // 4 KB;  idx = row*17 ^ kq  (= row*16 + (kq^row))
  float  muv[2][D_];      // 512 B
  float  rq0[BM], rq1[BM];
  float  red[4][BM];      // cross-wave rowsum
  float2 ckt[BN];         // fallback col consts
};

// Precompute per-column constants ck0/ck1 = s*|k - mu_c|^2 - neg into d_ws.
__global__ __launch_bounds__(256) void colconst_kernel(
    const float* __restrict__ k, const float* __restrict__ mask,
    const float* __restrict__ mu, float2* __restrict__ ck)
{
  int bh = blockIdx.x >> 3;
  int c  = (blockIdx.x & 7) * 256 + threadIdx.x;
  int b  = bh >> 3, h = bh & 7;
  const float s = -0.0625f;  // -0.5 / sqrt(64)
  const float* kp  = k  + ((size_t)bh * L_ + c) * D_;
  const float* mu0 = mu + (size_t)h * D_;
  const float* mu1 = mu + (size_t)(H_ * D_) + (size_t)h * D_;
  float s0 = 0.f, s1 = 0.f;
#pragma unroll
  for (int d = 0; d < D_; d += 4) {
    float4 kv = *reinterpret_cast<const float4*>(kp + d);
    float4 m0 = *reinterpret_cast<const float4*>(mu0 + d);
    float4 m1 = *reinterpret_cast<const float4*>(mu1 + d);
    float a;
    a = kv.x - m0.x; s0 += a * a;
    a = kv.y - m0.y; s0 += a * a;
    a = kv.z - m0.z; s0 += a * a;
    a = kv.w - m0.w; s0 += a * a;
    a = kv.x - m1.x; s1 += a * a;
    a = kv.y - m1.y; s1 += a * a;
    a = kv.z - m1.z; s1 += a * a;
    a = kv.w - m1.w; s1 += a * a;
  }
  float neg = 1.0e6f * (1.0f - mask[(size_t)b * L_ + c]);
  ck[(size_t)bh * L_ + c] = make_float2(s * s0 - neg, s * s1 - neg);
}

template <bool USE_WS>
__global__ __launch_bounds__(256, 2) void mg_kernel(
    const float* __restrict__ q, const float* __restrict__ k,
    const float* __restrict__ mask, const float* __restrict__ mu,
    const float* __restrict__ pi, const float2* __restrict__ ckw,
    float* __restrict__ out)
{
  extern __shared__ __align__(16) char smem_raw[];
  LdsT& S = *reinterpret_cast<LdsT*>(smem_raw);
  const int t = threadIdx.x;
  // XCD-chunked bijective swizzle (2048 % 8 == 0)
  int bid = blockIdx.x;
  int vwg = (bid & 7) * 256 + (bid >> 3);
  int bh  = vwg >> 7;
  int rb  = vwg & 127;
  int b = bh >> 3, h = bh & 7;
  int row0 = rb * BM;

  const int w  = t >> 6;   // wave 0..3 -> 64-col chunk within BN
  const int ln = t & 63;
  const int rg = ln >> 4;  // row group: rows 4rg..4rg+3
  const int ci = ln & 15;  // col lane within 16

  const float s   = -0.0625f;
  const float m2s = 0.125f;   // -2*s

  const float*  qb    = q + ((size_t)bh * L_ + row0) * D_;
  const float4* kb4   = (const float4*)(k + (size_t)bh * L_ * D_);
  const float*  maskb = mask + (size_t)b * L_;
  const float2* ckb   = ckw + (size_t)bh * L_;

  float pi0 = fminf(fmaxf(pi[0], 0.f), 1.f);
  float pi1 = fminf(fmaxf(pi[1], 0.f), 1.f);

  // ---- prologue: stage Q (swizzled) + mu ----
  {
    int row = t >> 4, kq = t & 15;
    float4 v = ((const float4*)qb)[row * 16 + kq];
    S.qt[row * 16 + (kq ^ row)] = v;
  }
  if (t < 2 * D_)
    S.muv[t >> 6][t & 63] =
        mu[(size_t)(t >> 6) * (H_ * D_) + (size_t)h * D_ + (t & 63)];
  __syncthreads();

  // per-row constants rq_c = s*q^2 + 2s*(q . mu_c)
  if (t < BM) {
    float a0 = 0.f, a1 = 0.f, a2 = 0.f;
#pragma unroll
    for (int dq = 0; dq < 16; ++dq) {
      float4 qv = S.qt[(t * 17) ^ dq];
      const float* m0 = &S.muv[0][4 * dq];
      const float* m1 = &S.muv[1][4 * dq];
      a0 += qv.x * qv.x + qv.y * qv.y + qv.z * qv.z + qv.w * qv.w;
      a1 += qv.x * m0[0] + qv.y * m0[1] + qv.z * m0[2] + qv.w * m0[3];
      a2 += qv.x * m1[0] + qv.y * m1[1] + qv.z * m1[2] + qv.w * m1[3];
    }
    S.rq0[t] = s * a0 + 2.f * s * a1;
    S.rq1[t] = s * a0 + 2.f * s * a2;
  }
  __syncthreads();

  float rq0r[4], rq1r[4];
#pragma unroll
  for (int rj = 0; rj < 4; ++rj) {
    rq0r[rj] = S.rq0[4 * rg + rj];
    rq1r[rj] = S.rq1[4 * rg + rj];
  }

  int kbase[4];
#pragma unroll
  for (int n = 0; n < 4; ++n) kbase[n] = (64 * w + 16 * n + ci) * 16 + ci;

  float av[NJ][4][4];   // unnormalized attn, fully static-indexed
  float rsum[4] = {0.f, 0.f, 0.f, 0.f};

#pragma unroll
  for (int j = 0; j < NJ; ++j) {
    __syncthreads();   // previous tile's compute done -> kt reusable
    // stage K tile: 64 KB via global_load_lds, pre-swizzled global source
#pragma unroll
    for (int i = 0; i < 16; ++i) {
      int u = t + 256 * i;
      int col = u >> 4, kqp = u & 15;
      const float4* gp =
          kb4 + ((size_t)(j * BN + col) * 16 + (kqp ^ (col & 15)));
      GLL16(gp, &S.kt[u]);
    }
    float2 cc[4];
    if (USE_WS) {
#pragma unroll
      for (int n = 0; n < 4; ++n)
        cc[n] = ckb[j * BN + 64 * w + 16 * n + ci];
    }
    __syncthreads();   // vmcnt(0) drained by compiler before barrier

    if (!USE_WS) {
      // compute col consts for col t from staged kt
      float s0 = 0.f, s1 = 0.f;
#pragma unroll 4
      for (int kq = 0; kq < 16; ++kq) {
        float4 kv = S.kt[t * 16 + (kq ^ (t & 15))];
        float4 m0 = *(const float4*)&S.muv[0][4 * kq];
        float4 m1 = *(const float4*)&S.muv[1][4 * kq];
        float a;
        a = kv.x - m0.x; s0 += a * a;
        a = kv.y - m0.y; s0 += a * a;
        a = kv.z - m0.z; s0 += a * a;
        a = kv.w - m0.w; s0 += a * a;
        a = kv.x - m1.x; s1 += a * a;
        a = kv.y - m1.y; s1 += a * a;
        a = kv.z - m1.z; s1 += a * a;
        a = kv.w - m1.w; s1 += a * a;
      }
      float neg = 1.0e6f * (1.0f - maskb[j * BN + t]);
      S.ckt[t] = make_float2(s * s0 - neg, s * s1 - neg);
      __syncthreads();
#pragma unroll
      for (int n = 0; n < 4; ++n) cc[n] = S.ckt[64 * w + 16 * n + ci];
    }

    // ---- GEMM micro-kernel: 4 rows x 4 cols per lane ----
    float dots[4][4] = {{0.f, 0.f, 0.f, 0.f}, {0.f, 0.f, 0.f, 0.f},
                        {0.f, 0.f, 0.f, 0.f}, {0.f, 0.f, 0.f, 0.f}};
#pragma unroll 4
    for (int kq = 0; kq < 16; ++kq) {
      float4 qv0 = S.qt[((4 * rg + 0) * 17) ^ kq];
      float4 qv1 = S.qt[((4 * rg + 1) * 17) ^ kq];
      float4 qv2 = S.qt[((4 * rg + 2) * 17) ^ kq];
      float4 qv3 = S.qt[((4 * rg + 3) * 17) ^ kq];
      float4 kv0 = S.kt[kbase[0] ^ kq];
      float4 kv1 = S.kt[kbase[1] ^ kq];
      float4 kv2 = S.kt[kbase[2] ^ kq];
      float4 kv3 = S.kt[kbase[3] ^ kq];
#define DOT4(acc, a, bb) acc += a.x*bb.x + a.y*bb.y + a.z*bb.z + a.w*bb.w
      DOT4(dots[0][0], qv0, kv0); DOT4(dots[0][1], qv0, kv1);
      DOT4(dots[0][2], qv0, kv2); DOT4(dots[0][3], qv0, kv3);
      DOT4(dots[1][0], qv1, kv0); DOT4(dots[1][1], qv1, kv1);
      DOT4(dots[1][2], qv1, kv2); DOT4(dots[1][3], qv1, kv3);
      DOT4(dots[2][0], qv2, kv0); DOT4(dots[2][1], qv2, kv1);
      DOT4(dots[2][2], qv2, kv2); DOT4(dots[2][3], qv2, kv3);
      DOT4(dots[3][0], qv3, kv0); DOT4(dots[3][1], qv3, kv1);
      DOT4(dots[3][2], qv3, kv2); DOT4(dots[3][3], qv3, kv3);
#undef DOT4
    }

    // epilogue: logits -> exp -> mix; accumulate row sums
#pragma unroll
    for (int rj = 0; rj < 4; ++rj) {
#pragma unroll
      for (int n = 0; n < 4; ++n) {
        float dd = m2s * dots[rj][n];
        float e0 = __expf(rq0r[rj] + cc[n].x + dd);
        float e1 = __expf(rq1r[rj] + cc[n].y + dd);
        float a  = pi0 * e0 + pi1 * e1;
        av[j][rj][n] = a;
        rsum[rj] += a;
      }
    }
  }

  // ---- row sums: reduce over 16 col-lanes, then across 4 waves ----
#pragma unroll
  for (int rj = 0; rj < 4; ++rj) {
    float v = rsum[rj];
    v += __shfl_xor(v, 1, 64);
    v += __shfl_xor(v, 2, 64);
    v += __shfl_xor(v, 4, 64);
    v += __shfl_xor(v, 8, 64);
    if (ci == 0) S.red[w][4 * rg + rj] = v;
  }
  __syncthreads();
  float inv[4];
#pragma unroll
  for (int rj = 0; rj < 4; ++rj) {
    int r = 4 * rg + rj;
    inv[rj] = 1.0f / (S.red[0][r] + S.red[1][r] + S.red[2][r] + S.red[3][r]);
  }

  // ---- normalized write-out ----
  float* ob = out + ((size_t)bh * L_ + row0) * L_;
#pragma unroll
  for (int j = 0; j < NJ; ++j) {
#pragma unroll
    for (int rj = 0; rj < 4; ++rj) {
      float* orow = ob + (size_t)(4 * rg + rj) * L_ + j * BN + 64 * w + ci;
#pragma unroll
      for (int n = 0; n < 4; ++n)
        orow[16 * n] = av[j][rj][n] * inv[rj];
    }
  }
}

extern "C" void kernel_launch(void* const* d_in, const int* in_sizes, int n_in,
                              void* d_out, int out_size, void* d_ws, size_t ws_size,
                              hipStream_t stream) {
  const float* q    = (const float*)d_in[0];
  const float* k    = (const float*)d_in[1];
  const float* mask = (const float*)d_in[2];
  const float* mu   = (const float*)d_in[3];
  const float* pi   = (const float*)d_in[4];
  float* out = (float*)d_out;

  const size_t smem = sizeof(LdsT);
  const size_t ck_bytes = (size_t)B_ * H_ * L_ * sizeof(float2);
  const bool use_ws = (ws_size >= ck_bytes) && (d_ws != nullptr);

  if (use_ws) {
    (void)hipFuncSetAttribute(reinterpret_cast<const void*>(&mg_kernel<true>),
                              hipFuncAttributeMaxDynamicSharedMemorySize, (int)smem);
    colconst_kernel<<<dim3(B_ * H_ * 8), dim3(256), 0, stream>>>(k, mask, mu, (float2*)d_ws);
    mg_kernel<true><<<dim3(B_ * H_ * (L_ / BM)), dim3(256), smem, stream>>>(
        q, k, mask, mu, pi, (const float2*)d_ws, out);
  } else {
    (void)hipFuncSetAttribute(reinterpret_cast<const void*>(&mg_kernel<false>),
                              hipFuncAttributeMaxDynamicSharedMemorySize, (int)smem);
    mg_kernel<false><<<dim3(B_ * H_ * (L_ / BM)), dim3(256), smem, stream>>>(
        q, k, mask, mu, pi, nullptr, out);
  }
}

// Round 3
// 150.994 us; speedup vs baseline: 4.6417x; 1.7785x over previous
//
#include <hip/hip_runtime.h>
#include <math.h>

#define B_ 2
#define H_ 8
#define L_ 2048
#define D_ 64
#define BM 16
#define BN 256
#define NJ (L_ / BN)   // 8 tiles

typedef __attribute__((ext_vector_type(8))) short short8;
typedef __attribute__((ext_vector_type(4))) float f4;

typedef __attribute__((address_space(3))) void lds_void_t;
typedef const __attribute__((address_space(1))) void gbl_void_t;
#define GLL16(gp, lp) __builtin_amdgcn_global_load_lds( \
    (gbl_void_t*)(gp), (lds_void_t*)(lp), 16, 0, 0)

#define MFMA16(a, b, c) __builtin_amdgcn_mfma_f32_16x16x32_bf16(a, b, c, 0, 0, 0)

struct LdsT {
  union {
    struct { short8 kth[BN * 8]; short8 ktl[BN * 8]; } k;  // 64 KB
    float att[16 * 516];                                    // 33 KB (store staging)
  } u;
  float muv[2][D_];
  float rq0[BM], rq1[BM];
  float red[4][BM];
  float2 ckt[BN];   // fallback col consts
};

__device__ inline void split8(const float4& a0, const float4& a1,
                              short8& hi, short8& lo) {
  float xs[8] = {a0.x, a0.y, a0.z, a0.w, a1.x, a1.y, a1.z, a1.w};
#pragma unroll
  for (int e = 0; e < 8; ++e) {
    unsigned u  = __float_as_uint(xs[e]);
    unsigned hb = (u + 0x8000u) & 0xFFFF0000u;     // RN-ish bf16, residual exact
    float    r  = xs[e] - __uint_as_float(hb);
    unsigned lb = (__float_as_uint(r) + 0x8000u) >> 16;
    hi[e] = (short)(hb >> 16);
    lo[e] = (short)lb;
  }
}

// Precompute: col consts ck = s*|k-mu_c|^2 - neg, and K as pre-swizzled
// bf16 hi/lo groups: wh[(bh*L + c)*8 + g'] = k[c][8*(g'^(c&7)) .. +7] (hi).
__global__ __launch_bounds__(256) void prep_kernel(
    const float* __restrict__ k, const float* __restrict__ mask,
    const float* __restrict__ mu, float2* __restrict__ ck,
    short8* __restrict__ wh, short8* __restrict__ wl)
{
  int bh = blockIdx.x >> 3;
  int c  = (blockIdx.x & 7) * 256 + threadIdx.x;
  int b  = bh >> 3, h = bh & 7;
  const float s = -0.0625f;  // -0.5 / sqrt(64)
  const float* kp  = k  + ((size_t)bh * L_ + c) * D_;
  const float* mu0 = mu + (size_t)h * D_;
  const float* mu1 = mu + (size_t)(H_ * D_) + (size_t)h * D_;
  float x[D_];
#pragma unroll
  for (int d = 0; d < D_; d += 4)
    *reinterpret_cast<float4*>(&x[d]) = *reinterpret_cast<const float4*>(kp + d);
  float s0 = 0.f, s1 = 0.f;
#pragma unroll
  for (int d = 0; d < D_; ++d) {
    float a = x[d] - mu0[d]; s0 += a * a;
    float bb = x[d] - mu1[d]; s1 += bb * bb;
  }
  float neg = 1.0e6f * (1.0f - mask[(size_t)b * L_ + c]);
  ck[(size_t)bh * L_ + c] = make_float2(s * s0 - neg, s * s1 - neg);
#pragma unroll
  for (int gp = 0; gp < 8; ++gp) {
    int g = gp ^ (c & 7);
    short8 hi, lo;
    split8(*reinterpret_cast<const float4*>(&x[8 * g]),
           *reinterpret_cast<const float4*>(&x[8 * g + 4]), hi, lo);
    size_t idx = ((size_t)bh * L_ + c) * 8 + gp;
    wh[idx] = hi;
    wl[idx] = lo;
  }
}

template <bool USE_WS>
__global__ __launch_bounds__(256, 2) void mg_kernel(
    const float* __restrict__ q, const float* __restrict__ kk,
    const float* __restrict__ mask, const float* __restrict__ mu,
    const float* __restrict__ pi, const float2* __restrict__ ckw,
    const short8* __restrict__ wh, const short8* __restrict__ wl,
    float* __restrict__ out)
{
  extern __shared__ __align__(16) char smem_raw[];
  LdsT& S = *reinterpret_cast<LdsT*>(smem_raw);
  const int t = threadIdx.x;
  int bid = blockIdx.x;
  int vwg = (bid & 7) * 256 + (bid >> 3);   // XCD-chunked, bijective (2048%8==0)
  int bh  = vwg >> 7;
  int rb  = vwg & 127;
  int b = bh >> 3, h = bh & 7;
  int row0 = rb * BM;

  const int w  = t >> 6;    // wave -> 64-col chunk of the 256-col tile
  const int ln = t & 63;
  const int ci = ln & 15;   // MFMA col lane / A row lane
  const int kg = ln >> 4;   // k-group lane

  const float s = -0.0625f;

  const float*  maskb = mask + (size_t)b * L_;
  const float2* ckb   = ckw + (size_t)bh * L_;
  const float4* kb4   = (const float4*)(kk + (size_t)bh * L_ * D_);
  const short8* whb   = wh + (size_t)bh * (L_ * 8);
  const short8* wlb   = wl + (size_t)bh * (L_ * 8);

  float pi0 = fminf(fmaxf(pi[0], 0.f), 1.f);
  float pi1 = fminf(fmaxf(pi[1], 0.f), 1.f);

  // stage mu
  if (t < 2 * D_)
    S.muv[t >> 6][t & 63] =
        mu[(size_t)(t >> 6) * (H_ * D_) + (size_t)h * D_ + (t & 63)];

  // A-fragments (Q rows, split bf16): lane = row ci, k-slice kg*8 within k-half
  short8 ah[2], al[2];
  {
    const float* qrow = q + ((size_t)bh * L_ + row0 + ci) * D_;
#pragma unroll
    for (int h2 = 0; h2 < 2; ++h2) {
      float4 a0 = *reinterpret_cast<const float4*>(qrow + 32 * h2 + kg * 8);
      float4 a1 = *reinterpret_cast<const float4*>(qrow + 32 * h2 + kg * 8 + 4);
      split8(a0, a1, ah[h2], al[h2]);
    }
  }
  __syncthreads();

  // per-row constants rq_c = s*q^2 + 2s*(q . mu_c)
  if (t < BM) {
    const float* qr = q + ((size_t)bh * L_ + row0 + t) * D_;
    float a0 = 0.f, a1 = 0.f, a2 = 0.f;
#pragma unroll
    for (int dq = 0; dq < 16; ++dq) {
      float4 qv = *reinterpret_cast<const float4*>(qr + 4 * dq);
      a0 += qv.x * qv.x + qv.y * qv.y + qv.z * qv.z + qv.w * qv.w;
      a1 += qv.x * S.muv[0][4*dq] + qv.y * S.muv[0][4*dq+1] +
            qv.z * S.muv[0][4*dq+2] + qv.w * S.muv[0][4*dq+3];
      a2 += qv.x * S.muv[1][4*dq] + qv.y * S.muv[1][4*dq+1] +
            qv.z * S.muv[1][4*dq+2] + qv.w * S.muv[1][4*dq+3];
    }
    S.rq0[t] = s * a0 + 2.f * s * a1;
    S.rq1[t] = s * a0 + 2.f * s * a2;
  }
  __syncthreads();

  float rq0r[4], rq1r[4];
#pragma unroll
  for (int reg = 0; reg < 4; ++reg) {
    rq0r[reg] = S.rq0[kg * 4 + reg];
    rq1r[reg] = S.rq1[kg * 4 + reg];
  }

  float av[NJ][4][4];
  float rsum[4] = {0.f, 0.f, 0.f, 0.f};

#pragma unroll
  for (int j = 0; j < NJ; ++j) {
    __syncthreads();   // prev tile's LDS reads done
    float2 cc[4];
    if (USE_WS) {
#pragma unroll
      for (int i = 0; i < 8; ++i)
        GLL16(whb + (size_t)j * (BN * 8) + t + 256 * i, &S.u.k.kth[t + 256 * i]);
#pragma unroll
      for (int i = 0; i < 8; ++i)
        GLL16(wlb + (size_t)j * (BN * 8) + t + 256 * i, &S.u.k.ktl[t + 256 * i]);
#pragma unroll
      for (int n = 0; n < 4; ++n)
        cc[n] = ckb[j * BN + w * 64 + 16 * n + ci];
      __syncthreads();
    } else {
      // reg-stage + in-kernel split/convert (fallback, no ws)
#pragma unroll
      for (int i = 0; i < 8; ++i) {
        int u = t + 256 * i;
        int col = u >> 3, gp = u & 7, g = gp ^ (col & 7);
        float4 x0 = kb4[(size_t)(j * BN + col) * 16 + 2 * g];
        float4 x1 = kb4[(size_t)(j * BN + col) * 16 + 2 * g + 1];
        short8 hi, lo;
        split8(x0, x1, hi, lo);
        S.u.k.kth[u] = hi;
        S.u.k.ktl[u] = lo;
      }
      {  // col consts for col t (global reads are L1/L2-hot)
        const float* kc = kk + ((size_t)bh * L_ + j * BN + t) * D_;
        float s0 = 0.f, s1 = 0.f;
#pragma unroll
        for (int dq = 0; dq < 16; ++dq) {
          float4 kv = *reinterpret_cast<const float4*>(kc + 4 * dq);
          float a;
          a = kv.x - S.muv[0][4*dq];   s0 += a * a;
          a = kv.y - S.muv[0][4*dq+1]; s0 += a * a;
          a = kv.z - S.muv[0][4*dq+2]; s0 += a * a;
          a = kv.w - S.muv[0][4*dq+3]; s0 += a * a;
          a = kv.x - S.muv[1][4*dq];   s1 += a * a;
          a = kv.y - S.muv[1][4*dq+1]; s1 += a * a;
          a = kv.z - S.muv[1][4*dq+2]; s1 += a * a;
          a = kv.w - S.muv[1][4*dq+3]; s1 += a * a;
        }
        float neg = 1.0e6f * (1.0f - maskb[j * BN + t]);
        S.ckt[t] = make_float2(s * s0 - neg, s * s1 - neg);
      }
      __syncthreads();
#pragma unroll
      for (int n = 0; n < 4; ++n) cc[n] = S.ckt[w * 64 + 16 * n + ci];
    }

    // MFMA: per 16-col block, 6 mfma (hi*hi, hi*lo, lo*hi over 2 k-halves)
#pragma unroll
    for (int n = 0; n < 4; ++n) {
      int base = (w * 64 + n * 16 + ci) * 8;
      int x7 = ci & 7;
      short8 b0h = S.u.k.kth[base + (kg ^ x7)];
      short8 b1h = S.u.k.kth[base + ((4 + kg) ^ x7)];
      short8 b0l = S.u.k.ktl[base + (kg ^ x7)];
      short8 b1l = S.u.k.ktl[base + ((4 + kg) ^ x7)];
      f4 acc = {0.f, 0.f, 0.f, 0.f};
      acc = MFMA16(ah[0], b0h, acc);
      acc = MFMA16(ah[1], b1h, acc);
      acc = MFMA16(ah[0], b0l, acc);
      acc = MFMA16(ah[1], b1l, acc);
      acc = MFMA16(al[0], b0h, acc);
      acc = MFMA16(al[1], b1h, acc);
#pragma unroll
      for (int reg = 0; reg < 4; ++reg) {
        float dd = 0.125f * acc[reg];   // -2s * (q.k)
        float e0 = __expf(rq0r[reg] + cc[n].x + dd);
        float e1 = __expf(rq1r[reg] + cc[n].y + dd);
        float a  = pi0 * e0 + pi1 * e1;
        av[j][n][reg] = a;
        rsum[reg] += a;
      }
    }
  }

  // row sums: reduce over 16 col-lanes (bits 0-3), then across 4 waves
#pragma unroll
  for (int reg = 0; reg < 4; ++reg) {
    float v = rsum[reg];
    v += __shfl_xor(v, 1, 64);
    v += __shfl_xor(v, 2, 64);
    v += __shfl_xor(v, 4, 64);
    v += __shfl_xor(v, 8, 64);
    if (ci == 0) S.red[w][kg * 4 + reg] = v;
  }
  __syncthreads();
  float inv[4];
#pragma unroll
  for (int reg = 0; reg < 4; ++reg) {
    int r = kg * 4 + reg;
    inv[reg] = 1.0f / (S.red[0][r] + S.red[1][r] + S.red[2][r] + S.red[3][r]);
  }

  // write-out via LDS transpose (K tiles dead -> reuse union), 4 chunks x 512 cols
  float* ob = out + ((size_t)bh * L_ + row0) * L_;
#pragma unroll
  for (int ch = 0; ch < 4; ++ch) {
    if (ch) __syncthreads();   // prev chunk's reads done
#pragma unroll
    for (int jj = 0; jj < 2; ++jj)
#pragma unroll
      for (int n = 0; n < 4; ++n)
#pragma unroll
        for (int reg = 0; reg < 4; ++reg)
          S.u.att[(kg * 4 + reg) * 516 + jj * 256 + w * 64 + n * 16 + ci] =
              av[2 * ch + jj][n][reg] * inv[reg];
    __syncthreads();
#pragma unroll
    for (int i = 0; i < 8; ++i) {
      int idx = i * 256 + t;
      int row = idx >> 7, c4 = idx & 127;
      float4 v = *reinterpret_cast<const float4*>(&S.u.att[row * 516 + c4 * 4]);
      *reinterpret_cast<float4*>(ob + (size_t)row * L_ + ch * 512 + c4 * 4) = v;
    }
  }
}

extern "C" void kernel_launch(void* const* d_in, const int* in_sizes, int n_in,
                              void* d_out, int out_size, void* d_ws, size_t ws_size,
                              hipStream_t stream) {
  const float* q    = (const float*)d_in[0];
  const float* k    = (const float*)d_in[1];
  const float* mask = (const float*)d_in[2];
  const float* mu   = (const float*)d_in[3];
  const float* pi   = (const float*)d_in[4];
  float* out = (float*)d_out;

  const size_t smem     = sizeof(LdsT);
  const size_t ck_bytes = (size_t)B_ * H_ * L_ * sizeof(float2);       // 256 KB
  const size_t wp_bytes = (size_t)B_ * H_ * L_ * D_ * sizeof(short);   // 4 MB each
  const bool use_ws = (ws_size >= ck_bytes + 2 * wp_bytes) && (d_ws != nullptr);

  if (use_ws) {
    float2* ck = (float2*)d_ws;
    short8* wh = (short8*)((char*)d_ws + ck_bytes);
    short8* wl = (short8*)((char*)d_ws + ck_bytes + wp_bytes);
    (void)hipFuncSetAttribute(reinterpret_cast<const void*>(&mg_kernel<true>),
                              hipFuncAttributeMaxDynamicSharedMemorySize, (int)smem);
    prep_kernel<<<dim3(B_ * H_ * 8), dim3(256), 0, stream>>>(k, mask, mu, ck, wh, wl);
    mg_kernel<true><<<dim3(B_ * H_ * (L_ / BM)), dim3(256), smem, stream>>>(
        q, k, mask, mu, pi, ck, wh, wl, out);
  } else {
    (void)hipFuncSetAttribute(reinterpret_cast<const void*>(&mg_kernel<false>),
                              hipFuncAttributeMaxDynamicSharedMemorySize, (int)smem);
    mg_kernel<false><<<dim3(B_ * H_ * (L_ / BM)), dim3(256), smem, stream>>>(
        q, k, mask, mu, pi, nullptr, nullptr, nullptr, out);
  }
}